// Round 2
// baseline (1499.788 us; speedup 1.0000x reference)
//
#include <hip/hip_runtime.h>
#include <hip/hip_bf16.h>
#include <math.h>

#define PW 160
#define PSQ 25600          // 160*160
#define NB 4
#define NX 307200          // NB*3*PSQ
#define NDIM 76800         // 3*PSQ

typedef __attribute__((ext_vector_type(8))) short short8;
typedef __attribute__((ext_vector_type(4))) float float4v;

struct TS40 { float t[40]; };
struct MC40 { float m[40]; float A; };

__device__ __forceinline__ short bf16s(float f) {
    return __builtin_bit_cast(short, __float2bfloat16(f));
}
__device__ __forceinline__ unsigned packbf(float a, float b) {
    return (unsigned)(unsigned short)bf16s(a) | ((unsigned)(unsigned short)bf16s(b) << 16);
}

// ---------------- time embedding
__global__ void emb_kernel(const float* __restrict__ wt, const float* __restrict__ bt,
                           float* __restrict__ emb, TS40 ts) {
    int r = blockIdx.x, k = threadIdx.x;   // 64 threads
    __shared__ float e64[64];
    float t = ts.t[r];
    int j = k & 31;
    float freq = expf(-0.29710775393471556f * (float)j);  // -ln(10000)/31
    float a = t * 999.0f * freq;
    e64[k] = (k < 32) ? sinf(a) : cosf(a);
    __syncthreads();
    if (k < 32) {
        float acc = bt[k];
        #pragma unroll 8
        for (int q = 0; q < 64; q++) acc += e64[q] * wt[q * 32 + k];
        emb[r * 32 + k] = acc;
    }
}

// ---------------- repack weights into MFMA A-fragment order (bf16)
__global__ void repack_kernel(const float* __restrict__ w1, const float* __restrict__ w2,
                              const float* __restrict__ w3, short* __restrict__ w1p,
                              short* __restrict__ w2p, short* __restrict__ w3p) {
    int tid = blockIdx.x * 256 + threadIdx.x;
    if (tid < 9216) {
        int j = tid & 7, co = (tid >> 3) & 31, q4 = tid >> 8;
        int tap = q4 >> 2, quad = q4 & 3, ci = quad * 8 + j;
        w2p[tid] = bf16s(w2[(co * 32 + ci) * 9 + tap]);
    }
    if (tid < 4608) {
        int j = tid & 7, co = (tid >> 3) & 15, q4 = tid >> 7;
        int tap = q4 >> 2, quad = q4 & 3, ci = quad * 8 + j;
        float v = (co < 3) ? w3[(co * 32 + ci) * 9 + tap] : 0.0f;
        w3p[tid] = bf16s(v);
    }
    if (tid < 1024) {
        int j = tid & 7, co = (tid >> 3) & 31, quad = tid >> 8;
        int k = quad * 8 + j;
        float v = 0.0f;
        if (k < 27) { int tap = (k * 11) >> 5; int ci = k - tap * 3; v = w1[(co * 3 + ci) * 9 + tap]; }
        w1p[tid] = bf16s(v);
    }
}

// ---------------- teps = raw conv1(eps), full image, bf16 [pix][32]
__global__ __launch_bounds__(256) void teps_conv1(
    const float* __restrict__ xin, const short* __restrict__ w1p,
    short* __restrict__ outH) {
    const int tile = blockIdx.x;
    const int ty0 = (tile / 10) * 16, tx0 = (tile % 10) * 16;
    const int tid = threadIdx.x;
    const int lane = tid & 63, wv = tid >> 6;
    const int n = lane & 15, quad = lane >> 4;
    __shared__ float sX[3 * 324];
    for (int idx = tid; idx < 3 * 324; idx += 256) {
        int ci = idx / 324, p = idx - ci * 324;
        int ly = p / 18, lx = p - ly * 18;
        int gy = ty0 + ly - 1, gx = tx0 + lx - 1;
        float v = 0.0f;
        if (gy >= 0 && gy < PW && gx >= 0 && gx < PW)
            v = xin[(size_t)ci * PSQ + gy * PW + gx];
        sX[idx] = v;
    }
    __syncthreads();
    int offj[8], valj[8];
    #pragma unroll
    for (int j = 0; j < 8; ++j) {
        int k = quad * 8 + j;
        valj[j] = (k < 27);
        int tap = (k * 11) >> 5; if (k >= 27) tap = 0;
        int ci = k - tap * 3;
        int dy = (tap * 11) >> 5, dx = tap - dy * 3;
        offj[j] = valj[j] ? (ci * 324 + dy * 18 + dx + n) : 0;
    }
    short8 a0 = *(const short8*)&w1p[(quad * 32 + n) * 8];
    short8 a1 = *(const short8*)&w1p[(quad * 32 + 16 + n) * 8];
    #pragma unroll
    for (int r = 0; r < 4; ++r) {
        int row = wv * 4 + r;
        short8 bb;
        #pragma unroll
        for (int j = 0; j < 8; ++j) {
            float v = valj[j] ? sX[offj[j] + row * 18] : 0.0f;
            bb[j] = bf16s(v);
        }
        float4v acc0 = {0.f, 0.f, 0.f, 0.f}, acc1 = {0.f, 0.f, 0.f, 0.f};
        acc0 = __builtin_amdgcn_mfma_f32_16x16x32_bf16(a0, bb, acc0, 0, 0, 0);
        acc1 = __builtin_amdgcn_mfma_f32_16x16x32_bf16(a1, bb, acc1, 0, 0, 0);
        int pix = (ty0 + row) * PW + tx0 + n;
        uint2 h0, h1v;
        h0.x = packbf(acc0[0], acc0[1]); h0.y = packbf(acc0[2], acc0[3]);
        h1v.x = packbf(acc1[0], acc1[1]); h1v.y = packbf(acc1[2], acc1[3]);
        *(uint2*)&outH[(size_t)pix * 32 + quad * 4] = h0;
        *(uint2*)&outH[(size_t)pix * 32 + 16 + quad * 4] = h1v;
    }
}

// ---------------- fully fused RK stage: conv1+conv2+conv3+divergence+RK update
// tile 8x16 out; regions: x 14x22, h1 12x20 (240px), h2 10x18 (180px)
// LDS 34080 B: H2/D2 alias H1/D1 (phase-2 results held in regs across a barrier);
// sOut aliases sX. -> 4 blocks/CU (one scheduling round for the 800-block grid).
__global__ __launch_bounds__(256, 4) void fused_stage(
    const float* __restrict__ xin, float* __restrict__ x0,
    float* __restrict__ xacc, float* __restrict__ xst,
    const short* __restrict__ w1p, const short* __restrict__ w2p,
    const short* __restrict__ w3p, const float* __restrict__ b1,
    const float* __restrict__ b2, const float* __restrict__ b3,
    const float* __restrict__ embr, const short* __restrict__ tepsb,
    const float* __restrict__ epsin, float* __restrict__ Sacc,
    float c1, float c2, float dt, int mode) {
    const int tile = blockIdx.x;            // 0..199
    const int b = blockIdx.y;
    const int oy = (tile / 10) * 8, ox = (tile % 10) * 16;
    const int tid = threadIdx.x;
    const int lane = tid & 63, wv = tid >> 6;
    const int n = lane & 15, quad = lane >> 4;

    __shared__ __align__(16) char smem[34080];
    short* sH1 = (short*)smem;                  // 240*64B = 15360 (ph1 W, ph2 R); late: sH2
    short* sD1 = (short*)(smem + 15360);        // 15360           (ph1 W, ph2 R); late: sD2
    short* sX  = (short*)(smem + 30720);        // bf16 x-tile 1848B (staging..ph1)
    short* sH2 = sH1;                           // alias (written after ph2 barrier)
    short* sD2 = sD1;                           // alias
    float* sOut = (float*)(smem + 30720);       // 3072B (ph3+) — aliases dead sX
    float* sBE = (float*)(smem + 33792);        // 32 f
    float* sB2 = (float*)(smem + 33920);        // 32 f
    float* sB3 = (float*)(smem + 34048);        // 3 f
    float* wsum = (float*)(smem + 34064);       // 4 f

    // ---- prefetch teps fragments for all phase-1 iterations (block-start issue)
    uint2 pt0[4], pt1[4];
    #pragma unroll
    for (int it = 0; it < 4; ++it) {
        int t = wv + it * 4;
        int tt = (t < 15) ? t : 0;
        int p = tt * 16 + n;
        int ry = p / 20, rx = p - ry * 20;
        int gy = oy - 2 + ry, gx = ox - 2 + rx;
        int ok = (t < 15) && gy >= 0 && gy < PW && gx >= 0 && gx < PW;
        size_t tbase = ok ? ((size_t)(gy * PW + gx) * 32) : 0;
        pt0[it] = *(const uint2*)&tepsb[tbase + quad * 4];
        pt1[it] = *(const uint2*)&tepsb[tbase + 16 + quad * 4];
    }

    // ---- prefetch final-phase operands (block-exclusive elements -> race-free)
    float pf_x[2], pf_e[2], pf_a[2], pf_x0[2];
    #pragma unroll
    for (int rep = 0; rep < 2; ++rep) {
        int idx = tid + rep * 256;
        int v = (idx < 384);
        int idc = v ? idx : 0;
        int c = idc >> 7, p128 = idc & 127;
        int ry = p128 >> 4, rx = p128 & 15;
        int pix = (oy + ry) * PW + ox + rx;
        size_t gi = (size_t)(b * 3 + c) * PSQ + pix;
        pf_x[rep] = v ? xin[gi] : 0.0f;
        pf_e[rep] = v ? epsin[c * PSQ + pix] : 0.0f;
        pf_a[rep] = 0.0f; pf_x0[rep] = 0.0f;
        if (mode >= 1) {
            pf_a[rep] = v ? xacc[gi] : 0.0f;
            pf_x0[rep] = v ? x0[gi] : 0.0f;
        }
    }

    if (tid < 32) { sBE[tid] = b1[tid] + embr[tid]; sB2[tid] = b2[tid]; }
    if (tid < 3) sB3[tid] = b3[tid];

    // ---- stage x region (zero-padded outside image), converted to bf16 once
    for (int idx = tid; idx < 3 * 308; idx += 256) {
        int ci = idx / 308, p = idx - ci * 308;
        int ly = p / 22, lx = p - ly * 22;
        int gy = oy - 3 + ly, gx = ox - 3 + lx;
        float v = 0.0f;
        if (gy >= 0 && gy < PW && gx >= 0 && gx < PW)
            v = xin[(size_t)(b * 3 + ci) * PSQ + gy * PW + gx];
        sX[idx] = bf16s(v);
    }
    __syncthreads();

    // ---- phase 1: conv1 over h1 region (240 px, 15 n-tiles)
    {
        int koff[8], kval[8];
        #pragma unroll
        for (int j = 0; j < 8; ++j) {
            int k = quad * 8 + j;
            kval[j] = (k < 27);
            int tap = (k * 11) >> 5; if (k >= 27) tap = 0;
            int ci = k - tap * 3;
            int dy = (tap * 11) >> 5, dx = tap - dy * 3;
            koff[j] = kval[j] ? (ci * 308 + dy * 22 + dx) : 0;
        }
        short8 a0 = *(const short8*)&w1p[(quad * 32 + n) * 8];
        short8 a1 = *(const short8*)&w1p[(quad * 32 + 16 + n) * 8];
        #pragma unroll
        for (int it = 0; it < 4; ++it) {
            int t = wv + it * 4;
            if (t < 15) {
                int p = t * 16 + n;                // < 240 always
                int ry = p / 20, rx = p - ry * 20;
                int gy = oy - 2 + ry, gx = ox - 2 + rx;
                int inimg = (gy >= 0 && gy < PW && gx >= 0 && gx < PW);
                int base = ry * 22 + rx;
                short8 bb;
                #pragma unroll
                for (int j = 0; j < 8; ++j)
                    bb[j] = kval[j] ? sX[koff[j] + base] : (short)0;
                float4v acc0 = {0.f, 0.f, 0.f, 0.f}, acc1 = {0.f, 0.f, 0.f, 0.f};
                acc0 = __builtin_amdgcn_mfma_f32_16x16x32_bf16(a0, bb, acc0, 0, 0, 0);
                acc1 = __builtin_amdgcn_mfma_f32_16x16x32_bf16(a1, bb, acc1, 0, 0, 0);
                int swz = (p & 7) << 4;
                #pragma unroll
                for (int mt = 0; mt < 2; ++mt) {
                    float4v* ac = mt ? &acc1 : &acc0;
                    uint2 t2 = mt ? pt1[it] : pt0[it];
                    int co0 = mt * 16 + quad * 4;
                    unsigned ts4[4] = {t2.x & 0xFFFFu, t2.x >> 16, t2.y & 0xFFFFu, t2.y >> 16};
                    unsigned hv[4], dv[4];
                    #pragma unroll
                    for (int g = 0; g < 4; ++g) {
                        float pre = (*ac)[g] + sBE[co0 + g];
                        hv[g] = inimg ? (unsigned)(unsigned short)bf16s(fmaxf(pre, 0.0f)) : 0u;
                        dv[g] = (inimg && pre > 0.0f) ? ts4[g] : 0u;
                    }
                    uint2 hw, dw;
                    hw.x = hv[0] | (hv[1] << 16); hw.y = hv[2] | (hv[3] << 16);
                    dw.x = dv[0] | (dv[1] << 16); dw.y = dv[2] | (dv[3] << 16);
                    int byw = ((p << 6) | (co0 << 1)) ^ swz;
                    *(uint2*)((char*)sH1 + byw) = hw;
                    *(uint2*)((char*)sD1 + byw) = dw;
                }
            }
        }
    }
    __syncthreads();

    // ---- phase 2: conv2 over h2 region (180 px, 12 n-tiles)
    // Two-pass over mt halves; results held in registers across a barrier so
    // H2/D2 can be written OVER the H1/D1 region (LDS alias).
    {
        uint2 heldH[2][3], heldD[2][3];
        #pragma unroll
        for (int mt = 0; mt < 2; ++mt) {
            short8 a2[9];
            #pragma unroll
            for (int tap = 0; tap < 9; ++tap)
                a2[tap] = *(const short8*)&w2p[((tap * 4 + quad) * 32 + mt * 16 + n) * 8];
            #pragma unroll
            for (int ti = 0; ti < 3; ++ti) {
                int p = (wv * 3 + ti) * 16 + n;
                int pc = p < 180 ? p : 179;
                int ry = pc / 18, rx = pc - ry * 18;
                float4v aP = {0.f,0.f,0.f,0.f}, aD = {0.f,0.f,0.f,0.f};
                #pragma unroll
                for (int tap = 0; tap < 9; ++tap) {
                    int dy = (tap * 11) >> 5, dx = tap - dy * 3;
                    int q = (ry + dy) * 20 + rx + dx;
                    int byr = ((q << 6) | (quad << 4)) ^ ((q & 7) << 4);
                    short8 bp = *(const short8*)((const char*)sH1 + byr);
                    short8 bd = *(const short8*)((const char*)sD1 + byr);
                    aP = __builtin_amdgcn_mfma_f32_16x16x32_bf16(a2[tap], bp, aP, 0, 0, 0);
                    aD = __builtin_amdgcn_mfma_f32_16x16x32_bf16(a2[tap], bd, aD, 0, 0, 0);
                }
                int gy = oy - 1 + ry, gx = ox - 1 + rx;
                int inimg = (gy >= 0 && gy < PW && gx >= 0 && gx < PW);
                int co0 = mt * 16 + quad * 4;
                unsigned hv[4], dv[4];
                #pragma unroll
                for (int g = 0; g < 4; ++g) {
                    float pre = aP[g] + sB2[co0 + g];
                    hv[g] = inimg ? (unsigned)(unsigned short)bf16s(fmaxf(pre, 0.0f)) : 0u;
                    dv[g] = (inimg && pre > 0.0f) ? (unsigned)(unsigned short)bf16s(aD[g]) : 0u;
                }
                heldH[mt][ti].x = hv[0] | (hv[1] << 16);
                heldH[mt][ti].y = hv[2] | (hv[3] << 16);
                heldD[mt][ti].x = dv[0] | (dv[1] << 16);
                heldD[mt][ti].y = dv[2] | (dv[3] << 16);
            }
        }
        __syncthreads();   // all H1/D1 reads complete before overwrite
        #pragma unroll
        for (int mt = 0; mt < 2; ++mt) {
            #pragma unroll
            for (int ti = 0; ti < 3; ++ti) {
                int p = (wv * 3 + ti) * 16 + n;
                if (p < 180) {
                    int co0 = mt * 16 + quad * 4;
                    int byw = ((p << 6) | (co0 << 1)) ^ ((p & 7) << 4);
                    *(uint2*)((char*)sH2 + byw) = heldH[mt][ti];
                    *(uint2*)((char*)sD2 + byw) = heldD[mt][ti];
                }
            }
        }
    }
    __syncthreads();

    // ---- phase 3: conv3 over out tile (128 px, 8 row-tiles) -> sOut
    {
        short8 a3[9];
        #pragma unroll
        for (int tap = 0; tap < 9; ++tap)
            a3[tap] = *(const short8*)&w3p[((tap * 4 + quad) * 16 + n) * 8];
        #pragma unroll
        for (int ti = 0; ti < 2; ++ti) {
            int ry = wv * 2 + ti;             // 0..7 = output row
            int rx = n;
            float4v aP = {0.f,0.f,0.f,0.f}, aD = {0.f,0.f,0.f,0.f};
            #pragma unroll
            for (int tap = 0; tap < 9; ++tap) {
                int dy = (tap * 11) >> 5, dx = tap - dy * 3;
                int q = (ry + dy) * 18 + rx + dx;
                int byr = ((q << 6) | (quad << 4)) ^ ((q & 7) << 4);
                short8 bp = *(const short8*)((const char*)sH2 + byr);
                short8 bd = *(const short8*)((const char*)sD2 + byr);
                aP = __builtin_amdgcn_mfma_f32_16x16x32_bf16(a3[tap], bp, aP, 0, 0, 0);
                aD = __builtin_amdgcn_mfma_f32_16x16x32_bf16(a3[tap], bd, aD, 0, 0, 0);
            }
            if (quad == 0) {
                int p128 = ry * 16 + rx;
                #pragma unroll
                for (int c = 0; c < 3; ++c) {
                    sOut[c * 128 + p128] = aP[c] + sB3[c];
                    sOut[384 + c * 128 + p128] = aD[c];
                }
            }
        }
    }
    __syncthreads();

    // ---- final: drift + RK update + divergence, all 256 threads, prefetched ops
    float s = 0.0f;
    #pragma unroll
    for (int rep = 0; rep < 2; ++rep) {
        int idx = tid + rep * 256;
        if (idx < 384) {
            int c = idx >> 7, p128 = idx & 127;
            int ry = p128 >> 4, rx = p128 & 15;
            int pix = (oy + ry) * PW + ox + rx;
            size_t gi = (size_t)(b * 3 + c) * PSQ + pix;
            float y = sOut[c * 128 + p128];
            float d = sOut[384 + c * 128 + p128];
            float xv = pf_x[rep];
            float k = -c1 * xv - c2 * y;
            if (mode == 0) {
                xacc[gi] = k;
                xst[gi] = xv + 0.5f * dt * k;     // xin == x0 at stage 0
            } else if (mode == 1) {
                xacc[gi] = pf_a[rep] + 2.0f * k;
                xst[gi] = pf_x0[rep] + 0.5f * dt * k;
            } else if (mode == 2) {
                xacc[gi] = pf_a[rep] + 2.0f * k;
                xst[gi] = pf_x0[rep] + dt * k;
            } else {
                x0[gi] = pf_x0[rep] + (dt / 6.0f) * (pf_a[rep] + k);
            }
            s += d * pf_e[rep];
        }
    }
    #pragma unroll
    for (int off = 32; off > 0; off >>= 1) s += __shfl_down(s, off);
    if (lane == 0) wsum[wv] = s;
    __syncthreads();
    if (tid == 0) atomicAdd(&Sacc[b], wsum[0] + wsum[1] + wsum[2] + wsum[3]);
}

// ---------------- sum z^2 per batch (parallel over 25 segments)
__global__ void sumz2_kernel(const float* __restrict__ x0, float* __restrict__ sumz2) {
    int b = blockIdx.x, seg = blockIdx.y, tid = threadIdx.x;
    const float* p = x0 + (size_t)b * NDIM + seg * 3072;
    float s = 0.0f;
    for (int i = tid; i < 3072; i += 256) { float v = p[i]; s += v * v; }
    #pragma unroll
    for (int off = 32; off > 0; off >>= 1) s += __shfl_down(s, off);
    __shared__ float wsum[4];
    if ((tid & 63) == 0) wsum[tid >> 6] = s;
    __syncthreads();
    if (tid == 0) atomicAdd(&sumz2[b], wsum[0] + wsum[1] + wsum[2] + wsum[3]);
}

// ---------------- final bpd
__global__ void bpd_kernel(const float* __restrict__ S, const float* __restrict__ sumz2,
                           float* __restrict__ out, MC40 mc) {
    int b = threadIdx.x;
    if (b >= NB) return;
    float lp = mc.A;
    for (int r = 0; r < 40; r++) lp -= mc.m[r] * S[r * 4 + b];
    float prior = -70574.479354f - 0.5f * sumz2[b];
    out[b] = -(prior + lp) * 1.8785164100960743e-5f;
}

extern "C" void kernel_launch(void* const* d_in, const int* in_sizes, int n_in,
                              void* d_out, int out_size, void* d_ws, size_t ws_size,
                              hipStream_t stream) {
    const float* patches = (const float*)d_in[0];
    const float* epsin = (const float*)d_in[1];
    const float* w1 = (const float*)d_in[2];
    const float* b1 = (const float*)d_in[3];
    const float* wt = (const float*)d_in[4];
    const float* bt = (const float*)d_in[5];
    const float* w2 = (const float*)d_in[6];
    const float* b2 = (const float*)d_in[7];
    const float* w3 = (const float*)d_in[8];
    const float* b3 = (const float*)d_in[9];
    float* outp = (float*)d_out;
    char* wsb = (char*)d_ws;

    float* Sbuf  = (float*)(wsb + 0);          // 160 f
    float* sumz2 = (float*)(wsb + 640);        // 4 f
    float* emb   = (float*)(wsb + 1024);       // 1280 f
    short* w1p   = (short*)(wsb + 6144);       // 1024 bf16
    short* w2p   = (short*)(wsb + 8192);       // 9216 bf16
    short* w3p   = (short*)(wsb + 26624);      // 4608 bf16
    short* tepsb = (short*)(wsb + 36864);      // 819200 bf16
    float* x0    = (float*)(wsb + 1675264);    // NX f
    float* xacc  = (float*)(wsb + 2904064);
    float* xst   = (float*)(wsb + 4132864);    // end ~5.4 MB

    const double dt = (1.0 - 1e-5) / 10.0;
    TS40 ts; MC40 mc;
    float c1a[40], c2a[40];
    double A = 0.0;
    const double wgt[4] = {1.0, 2.0, 2.0, 1.0};
    for (int i = 0; i < 10; i++) {
        double t0 = 1e-5 + dt * i;
        double tr[4] = {t0, t0 + 0.5 * dt, t0 + 0.5 * dt, t0 + dt};
        for (int s = 0; s < 4; s++) {
            int r = i * 4 + s;
            double t = tr[s];
            double beta = 0.1 + 19.9 * t;
            double lmc = -0.25 * t * t * 19.9 - 0.05 * t;
            double stdv = 1.0 - exp(2.0 * lmc);
            double g2 = beta * (1.0 - exp(4.0 * lmc));
            double c2 = 0.5 * g2 / stdv;
            ts.t[r] = (float)t;
            c1a[r] = (float)(0.5 * beta);
            c2a[r] = (float)c2;
            double coef = dt / 6.0 * wgt[s];
            mc.m[r] = (float)(coef * c2);
            A += coef * (-0.5 * beta * (double)NDIM);
        }
    }
    mc.A = (float)A;

    hipMemsetAsync(wsb, 0, 656, stream);  // Sbuf + sumz2
    hipMemcpyAsync(x0, patches, NX * sizeof(float), hipMemcpyDeviceToDevice, stream);

    emb_kernel<<<40, 64, 0, stream>>>(wt, bt, emb, ts);
    repack_kernel<<<36, 256, 0, stream>>>(w1, w2, w3, w1p, w2p, w3p);
    teps_conv1<<<100, 256, 0, stream>>>(epsin, w1p, tepsb);

    for (int i = 0; i < 10; i++) {
        for (int s = 0; s < 4; s++) {
            int r = i * 4 + s;
            const float* xin = (s == 0) ? x0 : xst;
            fused_stage<<<dim3(200, NB), 256, 0, stream>>>(
                xin, x0, xacc, xst, w1p, w2p, w3p, b1, b2, b3,
                emb + r * 32, tepsb, epsin, Sbuf + r * 4,
                c1a[r], c2a[r], (float)dt, s);
        }
    }
    sumz2_kernel<<<dim3(NB, 25), 256, 0, stream>>>(x0, sumz2);
    bpd_kernel<<<1, 64, 0, stream>>>(Sbuf, sumz2, outp, mc);
}

// Round 3
// 948.345 us; speedup vs baseline: 1.5815x; 1.5815x over previous
//
#include <hip/hip_runtime.h>
#include <hip/hip_bf16.h>
#include <math.h>

#define PW 160
#define PSQ 25600          // 160*160
#define NB 4
#define NX 307200          // NB*3*PSQ
#define NDIM 76800         // 3*PSQ

// 10x20 output tile geometry
#define TY 10
#define TX 20
#define XH 16
#define XW 26
#define XSZ 416            // XH*XW
#define H1H 14
#define H1W 24
#define H1N 336            // 21 n-tiles exactly
#define H2H 12
#define H2W 22
#define H2N 264            // 16.5 -> 17 n-tiles
#define OUTN 200           // 12.5 -> 13 n-tiles

typedef __attribute__((ext_vector_type(8))) short short8;
typedef __attribute__((ext_vector_type(4))) float float4v;

struct TS40 { float t[40]; };
struct MC40 { float m[40]; float A; };

__device__ __forceinline__ short bf16s(float f) {
    return __builtin_bit_cast(short, __float2bfloat16(f));
}
__device__ __forceinline__ unsigned packbf(float a, float b) {
    return (unsigned)(unsigned short)bf16s(a) | ((unsigned)(unsigned short)bf16s(b) << 16);
}

// ---------------- time embedding
__global__ void emb_kernel(const float* __restrict__ wt, const float* __restrict__ bt,
                           float* __restrict__ emb, TS40 ts) {
    int r = blockIdx.x, k = threadIdx.x;   // 64 threads
    __shared__ float e64[64];
    float t = ts.t[r];
    int j = k & 31;
    float freq = expf(-0.29710775393471556f * (float)j);  // -ln(10000)/31
    float a = t * 999.0f * freq;
    e64[k] = (k < 32) ? sinf(a) : cosf(a);
    __syncthreads();
    if (k < 32) {
        float acc = bt[k];
        #pragma unroll 8
        for (int q = 0; q < 64; q++) acc += e64[q] * wt[q * 32 + k];
        emb[r * 32 + k] = acc;
    }
}

// ---------------- repack weights into MFMA A-fragment order (bf16)
__global__ void repack_kernel(const float* __restrict__ w1, const float* __restrict__ w2,
                              const float* __restrict__ w3, short* __restrict__ w1p,
                              short* __restrict__ w2p, short* __restrict__ w3p) {
    int tid = blockIdx.x * 256 + threadIdx.x;
    if (tid < 9216) {
        int j = tid & 7, co = (tid >> 3) & 31, q4 = tid >> 8;
        int tap = q4 >> 2, quad = q4 & 3, ci = quad * 8 + j;
        w2p[tid] = bf16s(w2[(co * 32 + ci) * 9 + tap]);
    }
    if (tid < 4608) {
        int j = tid & 7, co = (tid >> 3) & 15, q4 = tid >> 7;
        int tap = q4 >> 2, quad = q4 & 3, ci = quad * 8 + j;
        float v = (co < 3) ? w3[(co * 32 + ci) * 9 + tap] : 0.0f;
        w3p[tid] = bf16s(v);
    }
    if (tid < 1024) {
        int j = tid & 7, co = (tid >> 3) & 31, quad = tid >> 8;
        int k = quad * 8 + j;
        float v = 0.0f;
        if (k < 27) { int tap = (k * 11) >> 5; int ci = k - tap * 3; v = w1[(co * 3 + ci) * 9 + tap]; }
        w1p[tid] = bf16s(v);
    }
}

// ---------------- teps = raw conv1(eps), full image, bf16 [pix][32]
__global__ __launch_bounds__(256) void teps_conv1(
    const float* __restrict__ xin, const short* __restrict__ w1p,
    short* __restrict__ outH) {
    const int tile = blockIdx.x;
    const int ty0 = (tile / 10) * 16, tx0 = (tile % 10) * 16;
    const int tid = threadIdx.x;
    const int lane = tid & 63, wv = tid >> 6;
    const int n = lane & 15, quad = lane >> 4;
    __shared__ float sX[3 * 324];
    for (int idx = tid; idx < 3 * 324; idx += 256) {
        int ci = idx / 324, p = idx - ci * 324;
        int ly = p / 18, lx = p - ly * 18;
        int gy = ty0 + ly - 1, gx = tx0 + lx - 1;
        float v = 0.0f;
        if (gy >= 0 && gy < PW && gx >= 0 && gx < PW)
            v = xin[(size_t)ci * PSQ + gy * PW + gx];
        sX[idx] = v;
    }
    __syncthreads();
    int offj[8], valj[8];
    #pragma unroll
    for (int j = 0; j < 8; ++j) {
        int k = quad * 8 + j;
        valj[j] = (k < 27);
        int tap = (k * 11) >> 5; if (k >= 27) tap = 0;
        int ci = k - tap * 3;
        int dy = (tap * 11) >> 5, dx = tap - dy * 3;
        offj[j] = valj[j] ? (ci * 324 + dy * 18 + dx + n) : 0;
    }
    short8 a0 = *(const short8*)&w1p[(quad * 32 + n) * 8];
    short8 a1 = *(const short8*)&w1p[(quad * 32 + 16 + n) * 8];
    #pragma unroll
    for (int r = 0; r < 4; ++r) {
        int row = wv * 4 + r;
        short8 bb;
        #pragma unroll
        for (int j = 0; j < 8; ++j) {
            float v = valj[j] ? sX[offj[j] + row * 18] : 0.0f;
            bb[j] = bf16s(v);
        }
        float4v acc0 = {0.f, 0.f, 0.f, 0.f}, acc1 = {0.f, 0.f, 0.f, 0.f};
        acc0 = __builtin_amdgcn_mfma_f32_16x16x32_bf16(a0, bb, acc0, 0, 0, 0);
        acc1 = __builtin_amdgcn_mfma_f32_16x16x32_bf16(a1, bb, acc1, 0, 0, 0);
        int pix = (ty0 + row) * PW + tx0 + n;
        uint2 h0, h1v;
        h0.x = packbf(acc0[0], acc0[1]); h0.y = packbf(acc0[2], acc0[3]);
        h1v.x = packbf(acc1[0], acc1[1]); h1v.y = packbf(acc1[2], acc1[3]);
        *(uint2*)&outH[(size_t)pix * 32 + quad * 4] = h0;
        *(uint2*)&outH[(size_t)pix * 32 + 16 + quad * 4] = h1v;
    }
}

// ---------------- fully fused RK stage: conv1+conv2+conv3+divergence+RK update
// 10x20 tile; x 16x26, h1 14x24 (336px), h2 12x22 (264px)
// LDS 77088 B -> exactly 2 blocks/CU; 512-block grid = exactly 2 blocks/CU
// everywhere (one perfectly balanced scheduling round).
__global__ __launch_bounds__(256, 2) void fused_stage(
    const float* __restrict__ xin, float* __restrict__ x0,
    float* __restrict__ xacc, float* __restrict__ xst,
    const short* __restrict__ w1p, const short* __restrict__ w2p,
    const short* __restrict__ w3p, const float* __restrict__ b1,
    const float* __restrict__ b2, const float* __restrict__ b3,
    const float* __restrict__ embr, const short* __restrict__ tepsb,
    const float* __restrict__ epsin, float* __restrict__ Sacc,
    float c1, float c2, float dt, int mode) {
    const int bid = blockIdx.x;             // 0..127
    const int tile = ((bid & 7) << 4) | (bid >> 3);   // XCD-aware swizzle (bijective)
    const int b = blockIdx.y;
    const int oy = (tile >> 3) * TY, ox = (tile & 7) * TX;
    const int tid = threadIdx.x;
    const int lane = tid & 63, wv = tid >> 6;
    const int n = lane & 15, quad = lane >> 4;

    __shared__ __align__(16) char smem[77088];
    short* sH1 = (short*)smem;                  // 336*64B = 21504
    short* sD1 = (short*)(smem + 21504);        // 21504
    short* sH2 = (short*)(smem + 43008);        // 264*64B = 16896
    short* sD2 = (short*)(smem + 59904);        // 16896
    short* sX  = (short*)(smem + 43008);        // bf16 x-tile 2496B (aliases sH2; dead after ph1)
    float* sOut = (float*)smem;                 // 4800B (ph3+) — aliases sH1 (dead after ph2)
    float* sBE = (float*)(smem + 76800);        // 32 f
    float* sB2 = (float*)(smem + 76928);        // 32 f
    float* sB3 = (float*)(smem + 77056);        // 3 f
    float* wsum = (float*)(smem + 77068);       // 4 f

    if (tid < 32) { sBE[tid] = b1[tid] + embr[tid]; sB2[tid] = b2[tid]; }
    if (tid < 3) sB3[tid] = b3[tid];

    // ---- stage x region (zero-padded outside image), converted to bf16 once
    for (int idx = tid; idx < 3 * XSZ; idx += 256) {
        int ci = idx / XSZ, p = idx - ci * XSZ;
        int ly = p / XW, lx = p - ly * XW;
        int gy = oy - 3 + ly, gx = ox - 3 + lx;
        float v = 0.0f;
        if (gy >= 0 && gy < PW && gx >= 0 && gx < PW)
            v = xin[(size_t)(b * 3 + ci) * PSQ + gy * PW + gx];
        sX[idx] = bf16s(v);
    }
    __syncthreads();

    // ---- phase 1: conv1 over h1 region (336 px, 21 n-tiles)
    {
        int koff[8], kval[8];
        #pragma unroll
        for (int j = 0; j < 8; ++j) {
            int k = quad * 8 + j;
            kval[j] = (k < 27);
            int tap = (k * 11) >> 5; if (k >= 27) tap = 0;
            int ci = k - tap * 3;
            int dy = (tap * 11) >> 5, dx = tap - dy * 3;
            koff[j] = kval[j] ? (ci * XSZ + dy * XW + dx) : 0;
        }
        short8 a0 = *(const short8*)&w1p[(quad * 32 + n) * 8];
        short8 a1 = *(const short8*)&w1p[(quad * 32 + 16 + n) * 8];
        for (int t = wv; t < 21; t += 4) {
            int p = t * 16 + n;                // < 336 always
            int ry = p / H1W, rx = p - ry * H1W;
            int gy = oy - 2 + ry, gx = ox - 2 + rx;
            int inimg = (gy >= 0 && gy < PW && gx >= 0 && gx < PW);
            // prefetch teps (clamped) BEFORE bb-build + MFMA
            size_t tbase = inimg ? ((size_t)(gy * PW + gx) * 32) : 0;
            uint2 t20 = *(const uint2*)&tepsb[tbase + quad * 4];
            uint2 t21 = *(const uint2*)&tepsb[tbase + 16 + quad * 4];
            int base = ry * XW + rx;
            short8 bb;
            #pragma unroll
            for (int j = 0; j < 8; ++j)
                bb[j] = kval[j] ? sX[koff[j] + base] : (short)0;
            float4v acc0 = {0.f, 0.f, 0.f, 0.f}, acc1 = {0.f, 0.f, 0.f, 0.f};
            acc0 = __builtin_amdgcn_mfma_f32_16x16x32_bf16(a0, bb, acc0, 0, 0, 0);
            acc1 = __builtin_amdgcn_mfma_f32_16x16x32_bf16(a1, bb, acc1, 0, 0, 0);
            int swz = (p & 7) << 4;
            #pragma unroll
            for (int mt = 0; mt < 2; ++mt) {
                float4v* ac = mt ? &acc1 : &acc0;
                uint2 t2 = mt ? t21 : t20;
                int co0 = mt * 16 + quad * 4;
                unsigned ts4[4] = {t2.x & 0xFFFFu, t2.x >> 16, t2.y & 0xFFFFu, t2.y >> 16};
                unsigned hv[4], dv[4];
                #pragma unroll
                for (int g = 0; g < 4; ++g) {
                    float pre = (*ac)[g] + sBE[co0 + g];
                    hv[g] = inimg ? (unsigned)(unsigned short)bf16s(fmaxf(pre, 0.0f)) : 0u;
                    dv[g] = (inimg && pre > 0.0f) ? ts4[g] : 0u;
                }
                uint2 hw, dw;
                hw.x = hv[0] | (hv[1] << 16); hw.y = hv[2] | (hv[3] << 16);
                dw.x = dv[0] | (dv[1] << 16); dw.y = dv[2] | (dv[3] << 16);
                int byw = ((p << 6) | (co0 << 1)) ^ swz;
                *(uint2*)((char*)sH1 + byw) = hw;
                *(uint2*)((char*)sD1 + byw) = dw;
            }
        }
    }
    __syncthreads();

    // ---- phase 2: conv2 over h2 region (264 px, 17 n-tiles), single-pass 4-chain
    {
        short8 a2[9][2];
        #pragma unroll
        for (int tap = 0; tap < 9; ++tap) {
            a2[tap][0] = *(const short8*)&w2p[((tap * 4 + quad) * 32 + n) * 8];
            a2[tap][1] = *(const short8*)&w2p[((tap * 4 + quad) * 32 + 16 + n) * 8];
        }
        for (int t = wv; t < 17; t += 4) {
            int p = t * 16 + n;
            int pc = p < H2N ? p : (H2N - 1);
            int ry = pc / H2W, rx = pc - ry * H2W;
            float4v aP0 = {0.f,0.f,0.f,0.f}, aP1 = {0.f,0.f,0.f,0.f};
            float4v aD0 = {0.f,0.f,0.f,0.f}, aD1 = {0.f,0.f,0.f,0.f};
            #pragma unroll
            for (int tap = 0; tap < 9; ++tap) {
                int dy = (tap * 11) >> 5, dx = tap - dy * 3;
                int q = (ry + dy) * H1W + rx + dx;
                int byr = ((q << 6) | (quad << 4)) ^ ((q & 7) << 4);
                short8 bp = *(const short8*)((const char*)sH1 + byr);
                short8 bd = *(const short8*)((const char*)sD1 + byr);
                aP0 = __builtin_amdgcn_mfma_f32_16x16x32_bf16(a2[tap][0], bp, aP0, 0, 0, 0);
                aP1 = __builtin_amdgcn_mfma_f32_16x16x32_bf16(a2[tap][1], bp, aP1, 0, 0, 0);
                aD0 = __builtin_amdgcn_mfma_f32_16x16x32_bf16(a2[tap][0], bd, aD0, 0, 0, 0);
                aD1 = __builtin_amdgcn_mfma_f32_16x16x32_bf16(a2[tap][1], bd, aD1, 0, 0, 0);
            }
            int gy = oy - 1 + ry, gx = ox - 1 + rx;
            int inimg = (gy >= 0 && gy < PW && gx >= 0 && gx < PW);
            if (p < H2N) {
                int swz = (p & 7) << 4;
                #pragma unroll
                for (int mt = 0; mt < 2; ++mt) {
                    float4v* acP = mt ? &aP1 : &aP0;
                    float4v* acD = mt ? &aD1 : &aD0;
                    int co0 = mt * 16 + quad * 4;
                    unsigned hv[4], dv[4];
                    #pragma unroll
                    for (int g = 0; g < 4; ++g) {
                        float pre = (*acP)[g] + sB2[co0 + g];
                        hv[g] = inimg ? (unsigned)(unsigned short)bf16s(fmaxf(pre, 0.0f)) : 0u;
                        dv[g] = (inimg && pre > 0.0f) ? (unsigned)(unsigned short)bf16s((*acD)[g]) : 0u;
                    }
                    uint2 hw, dw;
                    hw.x = hv[0] | (hv[1] << 16); hw.y = hv[2] | (hv[3] << 16);
                    dw.x = dv[0] | (dv[1] << 16); dw.y = dv[2] | (dv[3] << 16);
                    int byw = ((p << 6) | (co0 << 1)) ^ swz;
                    *(uint2*)((char*)sH2 + byw) = hw;
                    *(uint2*)((char*)sD2 + byw) = dw;
                }
            }
        }
    }
    __syncthreads();

    // ---- prefetch final-phase operands now (covered by ph3's MFMA work)
    float pf_x[3], pf_e[3], pf_a[3], pf_x0[3];
    #pragma unroll
    for (int rep = 0; rep < 3; ++rep) {
        int idx = tid + rep * 256;
        int v = (idx < 3 * OUTN);
        int idc = v ? idx : 0;
        int c = idc / OUTN, pp = idc - c * OUTN;
        int ry = pp / TX, rx = pp - ry * TX;
        int pix = (oy + ry) * PW + ox + rx;
        size_t gi = (size_t)(b * 3 + c) * PSQ + pix;
        pf_x[rep] = v ? xin[gi] : 0.0f;
        pf_e[rep] = v ? epsin[c * PSQ + pix] : 0.0f;
        pf_a[rep] = 0.0f; pf_x0[rep] = 0.0f;
        if (mode >= 1) {
            pf_a[rep] = v ? xacc[gi] : 0.0f;
            pf_x0[rep] = v ? x0[gi] : 0.0f;
        }
    }

    // ---- phase 3: conv3 over out tile (200 px, 13 n-tiles) -> sOut
    {
        short8 a3[9];
        #pragma unroll
        for (int tap = 0; tap < 9; ++tap)
            a3[tap] = *(const short8*)&w3p[((tap * 4 + quad) * 16 + n) * 8];
        for (int t = wv; t < 13; t += 4) {
            int p = t * 16 + n;
            int pc = p < OUTN ? p : (OUTN - 1);
            int ry = pc / TX, rx = pc - ry * TX;
            float4v aP = {0.f,0.f,0.f,0.f}, aD = {0.f,0.f,0.f,0.f};
            #pragma unroll
            for (int tap = 0; tap < 9; ++tap) {
                int dy = (tap * 11) >> 5, dx = tap - dy * 3;
                int q = (ry + dy) * H2W + rx + dx;
                int byr = ((q << 6) | (quad << 4)) ^ ((q & 7) << 4);
                short8 bp = *(const short8*)((const char*)sH2 + byr);
                short8 bd = *(const short8*)((const char*)sD2 + byr);
                aP = __builtin_amdgcn_mfma_f32_16x16x32_bf16(a3[tap], bp, aP, 0, 0, 0);
                aD = __builtin_amdgcn_mfma_f32_16x16x32_bf16(a3[tap], bd, aD, 0, 0, 0);
            }
            if (quad == 0 && p < OUTN) {
                #pragma unroll
                for (int c = 0; c < 3; ++c) {
                    sOut[c * OUTN + p] = aP[c] + sB3[c];
                    sOut[3 * OUTN + c * OUTN + p] = aD[c];
                }
            }
        }
    }
    __syncthreads();

    // ---- final: drift + RK update + divergence, all 256 threads, prefetched ops
    float s = 0.0f;
    #pragma unroll
    for (int rep = 0; rep < 3; ++rep) {
        int idx = tid + rep * 256;
        if (idx < 3 * OUTN) {
            int c = idx / OUTN, pp = idx - c * OUTN;
            int ry = pp / TX, rx = pp - ry * TX;
            int pix = (oy + ry) * PW + ox + rx;
            size_t gi = (size_t)(b * 3 + c) * PSQ + pix;
            float y = sOut[c * OUTN + pp];
            float d = sOut[3 * OUTN + c * OUTN + pp];
            float xv = pf_x[rep];
            float k = -c1 * xv - c2 * y;
            if (mode == 0) {
                xacc[gi] = k;
                xst[gi] = xv + 0.5f * dt * k;     // xin == x0 at stage 0
            } else if (mode == 1) {
                xacc[gi] = pf_a[rep] + 2.0f * k;
                xst[gi] = pf_x0[rep] + 0.5f * dt * k;
            } else if (mode == 2) {
                xacc[gi] = pf_a[rep] + 2.0f * k;
                xst[gi] = pf_x0[rep] + dt * k;
            } else {
                x0[gi] = pf_x0[rep] + (dt / 6.0f) * (pf_a[rep] + k);
            }
            s += d * pf_e[rep];
        }
    }
    #pragma unroll
    for (int off = 32; off > 0; off >>= 1) s += __shfl_down(s, off);
    if (lane == 0) wsum[wv] = s;
    __syncthreads();
    if (tid == 0) atomicAdd(&Sacc[b], wsum[0] + wsum[1] + wsum[2] + wsum[3]);
}

// ---------------- sum z^2 per batch (parallel over 25 segments)
__global__ void sumz2_kernel(const float* __restrict__ x0, float* __restrict__ sumz2) {
    int b = blockIdx.x, seg = blockIdx.y, tid = threadIdx.x;
    const float* p = x0 + (size_t)b * NDIM + seg * 3072;
    float s = 0.0f;
    for (int i = tid; i < 3072; i += 256) { float v = p[i]; s += v * v; }
    #pragma unroll
    for (int off = 32; off > 0; off >>= 1) s += __shfl_down(s, off);
    __shared__ float wsum[4];
    if ((tid & 63) == 0) wsum[tid >> 6] = s;
    __syncthreads();
    if (tid == 0) atomicAdd(&sumz2[b], wsum[0] + wsum[1] + wsum[2] + wsum[3]);
}

// ---------------- final bpd
__global__ void bpd_kernel(const float* __restrict__ S, const float* __restrict__ sumz2,
                           float* __restrict__ out, MC40 mc) {
    int b = threadIdx.x;
    if (b >= NB) return;
    float lp = mc.A;
    for (int r = 0; r < 40; r++) lp -= mc.m[r] * S[r * 4 + b];
    float prior = -70574.479354f - 0.5f * sumz2[b];
    out[b] = -(prior + lp) * 1.8785164100960743e-5f;
}

extern "C" void kernel_launch(void* const* d_in, const int* in_sizes, int n_in,
                              void* d_out, int out_size, void* d_ws, size_t ws_size,
                              hipStream_t stream) {
    const float* patches = (const float*)d_in[0];
    const float* epsin = (const float*)d_in[1];
    const float* w1 = (const float*)d_in[2];
    const float* b1 = (const float*)d_in[3];
    const float* wt = (const float*)d_in[4];
    const float* bt = (const float*)d_in[5];
    const float* w2 = (const float*)d_in[6];
    const float* b2 = (const float*)d_in[7];
    const float* w3 = (const float*)d_in[8];
    const float* b3 = (const float*)d_in[9];
    float* outp = (float*)d_out;
    char* wsb = (char*)d_ws;

    float* Sbuf  = (float*)(wsb + 0);          // 160 f
    float* sumz2 = (float*)(wsb + 640);        // 4 f
    float* emb   = (float*)(wsb + 1024);       // 1280 f
    short* w1p   = (short*)(wsb + 6144);       // 1024 bf16
    short* w2p   = (short*)(wsb + 8192);       // 9216 bf16
    short* w3p   = (short*)(wsb + 26624);      // 4608 bf16
    short* tepsb = (short*)(wsb + 36864);      // 819200 bf16
    float* x0    = (float*)(wsb + 1675264);    // NX f
    float* xacc  = (float*)(wsb + 2904064);
    float* xst   = (float*)(wsb + 4132864);    // end ~5.4 MB

    const double dt = (1.0 - 1e-5) / 10.0;
    TS40 ts; MC40 mc;
    float c1a[40], c2a[40];
    double A = 0.0;
    const double wgt[4] = {1.0, 2.0, 2.0, 1.0};
    for (int i = 0; i < 10; i++) {
        double t0 = 1e-5 + dt * i;
        double tr[4] = {t0, t0 + 0.5 * dt, t0 + 0.5 * dt, t0 + dt};
        for (int s = 0; s < 4; s++) {
            int r = i * 4 + s;
            double t = tr[s];
            double beta = 0.1 + 19.9 * t;
            double lmc = -0.25 * t * t * 19.9 - 0.05 * t;
            double stdv = 1.0 - exp(2.0 * lmc);
            double g2 = beta * (1.0 - exp(4.0 * lmc));
            double c2 = 0.5 * g2 / stdv;
            ts.t[r] = (float)t;
            c1a[r] = (float)(0.5 * beta);
            c2a[r] = (float)c2;
            double coef = dt / 6.0 * wgt[s];
            mc.m[r] = (float)(coef * c2);
            A += coef * (-0.5 * beta * (double)NDIM);
        }
    }
    mc.A = (float)A;

    hipMemsetAsync(wsb, 0, 656, stream);  // Sbuf + sumz2
    hipMemcpyAsync(x0, patches, NX * sizeof(float), hipMemcpyDeviceToDevice, stream);

    emb_kernel<<<40, 64, 0, stream>>>(wt, bt, emb, ts);
    repack_kernel<<<36, 256, 0, stream>>>(w1, w2, w3, w1p, w2p, w3p);
    teps_conv1<<<100, 256, 0, stream>>>(epsin, w1p, tepsb);

    for (int i = 0; i < 10; i++) {
        for (int s = 0; s < 4; s++) {
            int r = i * 4 + s;
            const float* xin = (s == 0) ? x0 : xst;
            fused_stage<<<dim3(128, NB), 256, 0, stream>>>(
                xin, x0, xacc, xst, w1p, w2p, w3p, b1, b2, b3,
                emb + r * 32, tepsb, epsin, Sbuf + r * 4,
                c1a[r], c2a[r], (float)dt, s);
        }
    }
    sumz2_kernel<<<dim3(NB, 25), 256, 0, stream>>>(x0, sumz2);
    bpd_kernel<<<1, 64, 0, stream>>>(Sbuf, sumz2, outp, mc);
}